// Round 5
// baseline (179.631 us; speedup 1.0000x reference)
//
#include <hip/hip_runtime.h>
#include <hip/hip_fp16.h>
#include <math.h>

// HieraFormer fused block, split-phase version:
//   transpose -> MFMA QKV proj -> qk_k (z=QK^T fp16 to global) ->
//   tau_k (entmax tau, wave-private Newton) -> pv_k (P on the fly + MFMA PV) -> LN.
// B=2, D_MODEL=384, H=3, D_K=128, N=2048.
#define DM   384
#define NH   3
#define DK   128
#define NSEQ 2048
#define BATCH 2
#define NTOK (BATCH*NSEQ)      // 4096
#define SEG  (BATCH*NSEQ*DM)   // 1572864 elements
#define NEWTON_IT 8

typedef __attribute__((ext_vector_type(8))) short     bf16x8;
typedef __attribute__((ext_vector_type(4))) float     f32x4;
typedef __attribute__((ext_vector_type(8))) _Float16  h8;
typedef __attribute__((ext_vector_type(2))) _Float16  h2v;

#if __has_builtin(__builtin_amdgcn_fdot2)
#define HAVE_FDOT2 1
#else
#define HAVE_FDOT2 0
#endif

__device__ __forceinline__ unsigned short f2bf(float f) {
  unsigned u = __builtin_bit_cast(unsigned, f);
  u += 0x7FFFu + ((u >> 16) & 1u);          // RNE
  return (unsigned short)(u >> 16);
}

// ---------------------------------------------------------------- transpose
__global__ __launch_bounds__(256) void transpose_k(const float* __restrict__ x,
                                                   float* __restrict__ xT,
                                                   unsigned short* __restrict__ xbf) {
  __shared__ float tile[32][33];
  int b  = blockIdx.z;
  int cB = blockIdx.y * 32;
  int nB = blockIdx.x * 32;
  int tx = threadIdx.x & 31, ty = threadIdx.x >> 5;
#pragma unroll
  for (int i = 0; i < 4; i++)
    tile[ty + i*8][tx] = x[((size_t)b*DM + cB + ty + i*8)*NSEQ + nB + tx];
  __syncthreads();
#pragma unroll
  for (int i = 0; i < 4; i++) {
    float v = tile[tx][ty + i*8];
    size_t row = (size_t)b*NSEQ + nB + ty + i*8;
    xT [row*DM + cB + tx] = v;
    xbf[row*DM + cB + tx] = f2bf(v);
  }
}

// ---------------------------------------------------------------- weight convert
__global__ __launch_bounds__(256) void wconv_k(const float* __restrict__ wq,
    const float* __restrict__ wk, const float* __restrict__ wv,
    unsigned short* __restrict__ wbf) {
  int pj = blockIdx.y;
  const float* src = (pj == 0) ? wq : (pj == 1) ? wk : wv;
  int i = (blockIdx.x * 256 + threadIdx.x) * 4;
  float4 v = *(const float4*)(src + i);
  ushort4 o;
  o.x = f2bf(v.x); o.y = f2bf(v.y); o.z = f2bf(v.z); o.w = f2bf(v.w);
  *(ushort4*)(wbf + (size_t)pj*DM*DM + i) = o;
}

// ---------------------------------------------------------------- MFMA projections
// Q,K -> bf16 [b][h][n][d];  V -> fp16 transposed VT [b][h][d][n].
__global__ __launch_bounds__(256) void proj_mfma_k(
    const unsigned short* __restrict__ xbf,   // [NTOK][DM]
    const unsigned short* __restrict__ wbf,   // [3][DM][DM]
    const float* __restrict__ bq, const float* __restrict__ bk, const float* __restrict__ bv,
    unsigned short* __restrict__ Qo, unsigned short* __restrict__ Ko,
    unsigned short* __restrict__ VTo) {      // VT stored as f16 bit-pattern
  int tid = threadIdx.x, lane = tid & 63, w = tid >> 6;
  int g = lane >> 4, li = lane & 15;
  int wr = w >> 1, wc = w & 1;
  int h  = blockIdx.y;
  int pj = blockIdx.z;
  const unsigned short* wp0 = wbf + (size_t)pj * DM * DM;
  const float* bias = (pj == 0) ? bq : (pj == 1) ? bk : bv;

  const unsigned short *Am, *Bn;
  int mB, nB;
  if (pj < 2) { Am = wp0; mB = h*128 + wr*64;          Bn = xbf; nB = blockIdx.x*128 + wc*64; }
  else        { Am = xbf; mB = blockIdx.x*128 + wr*64; Bn = wp0; nB = h*128 + wc*64; }

  f32x4 acc[4][4];
#pragma unroll
  for (int fi = 0; fi < 4; fi++)
#pragma unroll
    for (int fj = 0; fj < 4; fj++) acc[fi][fj] = (f32x4){0.f, 0.f, 0.f, 0.f};

#pragma unroll 2
  for (int ks = 0; ks < DM/32; ks++) {
    bf16x8 af[4], bf[4];
#pragma unroll
    for (int fi = 0; fi < 4; fi++)
      af[fi] = *(const bf16x8*)(Am + (size_t)(mB + fi*16 + li)*DM + ks*32 + g*8);
#pragma unroll
    for (int fj = 0; fj < 4; fj++)
      bf[fj] = *(const bf16x8*)(Bn + (size_t)(nB + fj*16 + li)*DM + ks*32 + g*8);
#pragma unroll
    for (int fi = 0; fi < 4; fi++)
#pragma unroll
      for (int fj = 0; fj < 4; fj++)
        acc[fi][fj] = __builtin_amdgcn_mfma_f32_16x16x32_bf16(af[fi], bf[fj], acc[fi][fj], 0, 0, 0);
  }

  if (pj < 2) {
    unsigned short* dst = (pj == 0) ? Qo : Ko;
#pragma unroll
    for (int fi = 0; fi < 4; fi++) {
      int o0 = mB + fi*16 + g*4;
      float4 bb = *(const float4*)(bias + o0);
      int d0 = o0 & 127;
#pragma unroll
      for (int fj = 0; fj < 4; fj++) {
        int tok = nB + fj*16 + li;
        int bb_ = tok >> 11, n = tok & 2047;
        ushort4 v4;
        v4.x = f2bf(acc[fi][fj][0] + bb.x);
        v4.y = f2bf(acc[fi][fj][1] + bb.y);
        v4.z = f2bf(acc[fi][fj][2] + bb.z);
        v4.w = f2bf(acc[fi][fj][3] + bb.w);
        *(ushort4*)(dst + ((size_t)(bb_*NH + h)*NSEQ + n)*DK + d0) = v4;
      }
    }
  } else {
#pragma unroll
    for (int fj = 0; fj < 4; fj++) {
      int o  = nB + fj*16 + li;
      float bb = bias[o];
      int d  = o & 127;
#pragma unroll
      for (int fi = 0; fi < 4; fi++) {
        int tok0 = mB + fi*16 + g*4;
        int bb_ = tok0 >> 11, n0 = tok0 & 2047;
        ushort4 v4;
        v4.x = __builtin_bit_cast(unsigned short, (_Float16)(acc[fi][fj][0] + bb));
        v4.y = __builtin_bit_cast(unsigned short, (_Float16)(acc[fi][fj][1] + bb));
        v4.z = __builtin_bit_cast(unsigned short, (_Float16)(acc[fi][fj][2] + bb));
        v4.w = __builtin_bit_cast(unsigned short, (_Float16)(acc[fi][fj][3] + bb));
        *(ushort4*)(VTo + ((size_t)(bb_*NH + h)*DK + d)*NSEQ + n0) = v4;
      }
    }
  }
}

// ---------------------------------------------------------------- K1: z = QK^T
// Swapped operands: A = K rows (m = k-index), B = Q rows (n = q-index) so each
// lane's 4 acc regs are 4 consecutive k at fixed q -> ushort4 into z[q][k].
// Grid (16 ktile, 16 qtile, 6 bh), block 256 (4 waves 2x2 of 64x64). No LDS.
__global__ __launch_bounds__(256) void qk_k(const unsigned short* __restrict__ Qb,
    const unsigned short* __restrict__ Kb, _Float16* __restrict__ Z) {
  int tid = threadIdx.x, lane = tid & 63, w = tid >> 6;
  int g = lane >> 4, li = lane & 15;
  int wr = w >> 1, wc = w & 1;
  int kt = blockIdx.x, qt = blockIdx.y, bh = blockIdx.z;
  const unsigned short* Qh = Qb + (size_t)bh * NSEQ * DK;
  const unsigned short* Kh = Kb + (size_t)bh * NSEQ * DK;
  _Float16* Zh = Z + (size_t)bh * NSEQ * NSEQ;
  int kB = kt*128 + wr*64, qB = qt*128 + wc*64;
  const float zs = 0.044194173824159216f;   // 0.5 / sqrt(128)

  f32x4 acc[4][4];
#pragma unroll
  for (int fi = 0; fi < 4; fi++)
#pragma unroll
    for (int fj = 0; fj < 4; fj++) acc[fi][fj] = (f32x4){0.f, 0.f, 0.f, 0.f};

#pragma unroll
  for (int ks = 0; ks < 4; ks++) {
    bf16x8 af[4], bf[4];
#pragma unroll
    for (int fi = 0; fi < 4; fi++)
      af[fi] = *(const bf16x8*)(Kh + (size_t)(kB + fi*16 + li)*DK + ks*32 + g*8);
#pragma unroll
    for (int fj = 0; fj < 4; fj++)
      bf[fj] = *(const bf16x8*)(Qh + (size_t)(qB + fj*16 + li)*DK + ks*32 + g*8);
#pragma unroll
    for (int fi = 0; fi < 4; fi++)
#pragma unroll
      for (int fj = 0; fj < 4; fj++)
        acc[fi][fj] = __builtin_amdgcn_mfma_f32_16x16x32_bf16(af[fi], bf[fj], acc[fi][fj], 0, 0, 0);
  }

#pragma unroll
  for (int fj = 0; fj < 4; fj++) {
    int q = qB + fj*16 + li;
#pragma unroll
    for (int fi = 0; fi < 4; fi++) {
      int k0 = kB + fi*16 + g*4;
      ushort4 v4;
      v4.x = __builtin_bit_cast(unsigned short, (_Float16)(acc[fi][fj][0] * zs));
      v4.y = __builtin_bit_cast(unsigned short, (_Float16)(acc[fi][fj][1] * zs));
      v4.z = __builtin_bit_cast(unsigned short, (_Float16)(acc[fi][fj][2] * zs));
      v4.w = __builtin_bit_cast(unsigned short, (_Float16)(acc[fi][fj][3] * zs));
      *(ushort4*)(Zh + (size_t)q*NSEQ + k0) = v4;
    }
  }
}

// ---------------------------------------------------------------- entmax helpers
__device__ __forceinline__ void scan_row(const h2v* zh, float tau,
                                         float& f, float& g, float& c) {
  float ff = 0.f, gg = 0.f, cc = 0.f;
#if HAVE_FDOT2
  _Float16 th = (_Float16)tau;
  h2v t2 = {th, th};
  h2v zero2 = {(_Float16)0.f, (_Float16)0.f};
  h2v one2  = {(_Float16)1.f, (_Float16)1.f};
  h2v big2  = {(_Float16)60000.f, (_Float16)60000.f};
#pragma unroll
  for (int i = 0; i < 16; i++) {
    h2v d = __builtin_elementwise_max(zh[i] - t2, zero2);
    ff = __builtin_amdgcn_fdot2(d, d, ff, false);
    gg = __builtin_amdgcn_fdot2(d, one2, gg, false);
    h2v mm = __builtin_elementwise_min(d * big2, one2);
    cc = __builtin_amdgcn_fdot2(mm, one2, cc, false);
  }
#else
#pragma unroll
  for (int i = 0; i < 16; i++) {
#pragma unroll
    for (int j = 0; j < 2; j++) {
      float z = (float)zh[i][j];
      float d = fmaxf(z - tau, 0.f);
      ff = fmaf(d, d, ff);
      gg += d;
      cc += (d > 0.f) ? 1.f : 0.f;
    }
  }
#endif
  f = ff; g = gg; c = cc;
}

// frozen-support exact solve (Michelot step); Newton-back if overshot
__device__ __forceinline__ float nstep(float tau, float f, float g, float c, float m) {
  float num  = f - 1.0f;
  float disc = fmaxf(g*g - c*num, 0.f);
  float den  = (num >= 0.f) ? (g + sqrtf(disc)) : (2.0f * g);
  float t = tau + num / fmaxf(den, 1e-12f);
  return fminf(t, m - 0.01f);    // tau* <= m - 1/sqrt(2048); keeps support >= 1
}

// ---------------------------------------------------------------- K2: tau per row
// Wave-private: each wave owns 2 full rows in registers (32 halves/lane/row).
// No LDS, no barriers. Grid 1536 blocks x 256 thr (4 waves, 8 rows/block).
__global__ __launch_bounds__(256) void tau_k(const _Float16* __restrict__ Z,
                                             float* __restrict__ tau) {
  int lane = threadIdx.x & 63, w = threadIdx.x >> 6;
  size_t rA = (size_t)blockIdx.x * 8 + w*2, rB = rA + 1;
  union { h8 v[4]; h2v h[16]; } ua, ub;
#pragma unroll
  for (int i = 0; i < 4; i++) {
    ua.v[i] = *(const h8*)(Z + rA*NSEQ + i*512 + lane*8);
    ub.v[i] = *(const h8*)(Z + rB*NSEQ + i*512 + lane*8);
  }
  h2v mxa = ua.h[0], mxb = ub.h[0];
#pragma unroll
  for (int i = 1; i < 16; i++) {
    mxa = __builtin_elementwise_max(mxa, ua.h[i]);
    mxb = __builtin_elementwise_max(mxb, ub.h[i]);
  }
  float mA = fmaxf((float)mxa[0], (float)mxa[1]);
  float mB = fmaxf((float)mxb[0], (float)mxb[1]);
#pragma unroll
  for (int off = 32; off > 0; off >>= 1) {
    mA = fmaxf(mA, __shfl_xor(mA, off));
    mB = fmaxf(mB, __shfl_xor(mB, off));
  }
  float tauA = mA - 1.0f, tauB = mB - 1.0f;
  for (int it = 0; it < NEWTON_IT; ++it) {
    float fA, gA, cA, fB, gB, cB;
    scan_row(ua.h, tauA, fA, gA, cA);
    scan_row(ub.h, tauB, fB, gB, cB);
#pragma unroll
    for (int off = 32; off > 0; off >>= 1) {
      fA += __shfl_xor(fA, off); gA += __shfl_xor(gA, off); cA += __shfl_xor(cA, off);
      fB += __shfl_xor(fB, off); gB += __shfl_xor(gB, off); cB += __shfl_xor(cB, off);
    }
    tauA = nstep(tauA, fA, gA, cA, mA);
    tauB = nstep(tauB, fB, gB, cB, mB);
  }
  if (lane == 0) { tau[rA] = tauA; tau[rB] = tauB; }
}

// ---------------------------------------------------------------- K3: O = P.V
// P rebuilt on the fly: p = relu(z - tau_row)^2 in fp16. Waves split the
// d-dimension (wave w owns d in [w*32, w*32+32)) -> no cross-wave reduce,
// no LDS, no barriers. Grid (128 qtile, 6 bh), block 256.
__global__ __launch_bounds__(256) void pv_k(const _Float16* __restrict__ Z,
    const float* __restrict__ tau, const _Float16* __restrict__ VTb,
    float* __restrict__ AO) {
  int tid = threadIdx.x, lane = tid & 63, w = tid >> 6;
  int g = lane >> 4, li = lane & 15;
  int qbase = blockIdx.x * 16, bh = blockIdx.y;
  const _Float16* Zh  = Z   + ((size_t)bh * NSEQ + qbase) * NSEQ;
  const _Float16* VTh = VTb + (size_t)bh * DK * NSEQ;

  float tli = tau[(size_t)bh * NSEQ + qbase + li];
  _Float16 th = (_Float16)tli;
  h2v t2 = {th, th};
  h2v zero2 = {(_Float16)0.f, (_Float16)0.f};

  f32x4 acc[2];
  acc[0] = (f32x4){0.f, 0.f, 0.f, 0.f};
  acc[1] = (f32x4){0.f, 0.f, 0.f, 0.f};

  for (int kc = 0; kc < NSEQ; kc += 32) {
    union { h8 v; h2v h[4]; } u;
    u.v = *(const h8*)(Zh + (size_t)li*NSEQ + kc + g*8);
#pragma unroll
    for (int j = 0; j < 4; j++) {
      h2v d = __builtin_elementwise_max(u.h[j] - t2, zero2);
      u.h[j] = d * d;
    }
#pragma unroll
    for (int dt = 0; dt < 2; dt++) {
      h8 bv = *(const h8*)(VTh + (size_t)(w*32 + dt*16 + li)*NSEQ + kc + g*8);
      acc[dt] = __builtin_amdgcn_mfma_f32_16x16x32_f16(u.v, bv, acc[dt], 0, 0, 0);
    }
  }

  int b = bh / NH, h = bh % NH;
#pragma unroll
  for (int dt = 0; dt < 2; dt++) {
    int d = h*DK + w*32 + dt*16 + li;
#pragma unroll
    for (int r = 0; r < 4; r++)
      AO[((size_t)b*NSEQ + qbase + g*4 + r)*DM + d] = acc[dt][r];
  }
}

// ---------------------------------------------------------------- LN + residual
__global__ __launch_bounds__(256) void ln_k(const float* __restrict__ AO,
    const float* __restrict__ xT, const float* __restrict__ ga,
    const float* __restrict__ gb, float* __restrict__ outp) {
  int lane = threadIdx.x & 63;
  int wave = threadIdx.x >> 6;
  int row  = blockIdx.x * 4 + wave;
  const float* ao = AO + (size_t)row*DM;
  float2 c0 = *(const float2*)(ao + lane*2);
  float2 c1 = *(const float2*)(ao + 128 + lane*2);
  float2 c2 = *(const float2*)(ao + 256 + lane*2);
  float s  = c0.x + c0.y + c1.x + c1.y + c2.x + c2.y;
  float ss = c0.x*c0.x + c0.y*c0.y + c1.x*c1.x + c1.y*c1.y + c2.x*c2.x + c2.y*c2.y;
#pragma unroll
  for (int off = 32; off > 0; off >>= 1) {
    s  += __shfl_xor(s,  off);
    ss += __shfl_xor(ss, off);
  }
  float mean = s * (1.0f / 384.0f);
  float var  = (ss - 384.0f*mean*mean) * (1.0f / 383.0f);   // Bessel (n-1)
  var = fmaxf(var, 0.f);
  float inv = 1.0f / (sqrtf(var) + 1e-6f);                  // eps added to STD
  const float* xr = xT + (size_t)row*DM;
  float* op = outp + (size_t)row*DM;
#pragma unroll
  for (int ch = 0; ch < 3; ch++) {
    int i0 = ch*128 + lane*2;
    float2 g  = *(const float2*)(ga + i0);
    float2 bb = *(const float2*)(gb + i0);
    float2 xv = *(const float2*)(xr + i0);
    float2 av = (ch == 0) ? c0 : (ch == 1) ? c1 : c2;
    float2 o;
    o.x = g.x*(av.x - mean)*inv + bb.x + xv.x;
    o.y = g.y*(av.y - mean)*inv + bb.y + xv.y;
    *(float2*)(op + i0) = o;
  }
}

// ---------------------------------------------------------------- launch
extern "C" void kernel_launch(void* const* d_in, const int* in_sizes, int n_in,
                              void* d_out, int out_size, void* d_ws, size_t ws_size,
                              hipStream_t stream) {
  const float* x  = (const float*)d_in[0];
  const float* wq = (const float*)d_in[1];
  const float* bq = (const float*)d_in[2];
  const float* wk = (const float*)d_in[3];
  const float* bk = (const float*)d_in[4];
  const float* wv = (const float*)d_in[5];
  const float* bv = (const float*)d_in[6];
  const float* la = (const float*)d_in[7];
  const float* lb = (const float*)d_in[8];
  float* out = (float*)d_out;

  // ws: xT f32 | AO f32 | Qb bf16 | Kb bf16 | VT f16 | xbf bf16 | wbf bf16 | Z f16 | tau f32
  char* wsb = (char*)d_ws;
  float* xT = (float*)wsb;
  float* AO = (float*)(wsb + (size_t)SEG*4);
  unsigned short* Qb  = (unsigned short*)(wsb + (size_t)SEG*8);
  unsigned short* Kb  = (unsigned short*)(wsb + (size_t)SEG*8 + (size_t)SEG*2);
  unsigned short* VT  = (unsigned short*)(wsb + (size_t)SEG*8 + (size_t)SEG*4);
  unsigned short* xbf = (unsigned short*)(wsb + (size_t)SEG*8 + (size_t)SEG*6);
  unsigned short* wbf = (unsigned short*)(wsb + (size_t)SEG*8 + (size_t)SEG*8);
  char* zb = wsb + (size_t)SEG*16 + (size_t)3*DM*DM*2;
  _Float16* Z   = (_Float16*)zb;                                   // 6*2048*2048*2 B
  float*    taub = (float*)(zb + (size_t)BATCH*NH*NSEQ*NSEQ*2);    // 12288 f32

  hipLaunchKernelGGL(transpose_k, dim3(NSEQ/32, DM/32, BATCH), dim3(256), 0, stream,
                     x, xT, xbf);
  hipLaunchKernelGGL(wconv_k, dim3(DM*DM/1024, 3), dim3(256), 0, stream, wq, wk, wv, wbf);
  hipLaunchKernelGGL(proj_mfma_k, dim3(NTOK/128, NH, 3), dim3(256), 0, stream,
                     xbf, wbf, bq, bk, bv, Qb, Kb, VT);
  hipLaunchKernelGGL(qk_k, dim3(NSEQ/128, NSEQ/128, BATCH*NH), dim3(256), 0, stream,
                     Qb, Kb, Z);
  hipLaunchKernelGGL(tau_k, dim3(BATCH*NH*NSEQ/8), dim3(256), 0, stream, Z, taub);
  hipLaunchKernelGGL(pv_k, dim3(NSEQ/16, BATCH*NH), dim3(256), 0, stream,
                     Z, taub, (const _Float16*)VT, AO);
  hipLaunchKernelGGL(ln_k, dim3(BATCH*NSEQ/4), dim3(256), 0, stream, AO, xT, la, lb, out);
}